// Round 2
// baseline (1312.237 us; speedup 1.0000x reference)
//
#include <hip/hip_runtime.h>

// Problem constants
#define BATCH 256
#define SEQ   128
#define IDIM  1024     // 256 + 768
#define HDIM  1024
#define G3    3072     // 3*HDIM
#define RS    100      // padded row stride (dwords) of split-K LDS buffer

typedef __attribute__((ext_vector_type(8))) short bf16x8;
typedef __attribute__((ext_vector_type(4))) short s16x4;
typedef __attribute__((ext_vector_type(4))) float f32x4;

__device__ __forceinline__ short f2bf(float f) {
    union { float f; unsigned u; } x; x.f = f;
    unsigned r = x.u + 0x7fffu + ((x.u >> 16) & 1u);   // RNE
    return (short)(r >> 16);
}
__device__ __forceinline__ float bf2f(unsigned short u) {
    union { unsigned u; float f; } x; x.u = ((unsigned)u) << 16;
    return x.f;
}

// LLC-coherent ops: write-through / bypass L1+L2, coherent at Infinity Cache.
__device__ __forceinline__ void st_llc_b64(short* p, s16x4 v) {
    asm volatile("global_store_dwordx2 %0, %1, off sc0 sc1" :: "v"(p), "v"(v) : "memory");
}
__device__ __forceinline__ void st_llc_b32(unsigned* p, unsigned v) {
    asm volatile("global_store_dword %0, %1, off sc0 sc1" :: "v"(p), "v"(v) : "memory");
}
#define LDH(dst, p, OFF) \
    asm volatile("global_load_dwordx4 %0, %1, off offset:" OFF " sc0 sc1" \
                 : "=v"(dst) : "v"(p))
#define LDX(dst, p) \
    asm volatile("global_load_dwordx2 %0, %1, off" : "=v"(dst) : "v"(p))

// ---------------------------------------------------------------------------
// Kernel 1: convert W_ih and W_hh (f32, row-major (3072,1024)) to bf16.
__global__ void cvt_w(const float* __restrict__ wih, const float* __restrict__ whh,
                      short* __restrict__ wihb, short* __restrict__ whhb) {
    int i = blockIdx.x * 256 + threadIdx.x;
    const float* s; short* d; int j;
    if (i < 786432) { s = wih; d = wihb; j = i; }
    else            { s = whh; d = whhb; j = i - 786432; }
    const float4 v = *((const float4*)s + j);
    s16x4 o;
    o[0] = f2bf(v.x); o[1] = f2bf(v.y); o[2] = f2bf(v.z); o[3] = f2bf(v.w);
    *(s16x4*)(d + (size_t)j * 4) = o;
}

// ---------------------------------------------------------------------------
// Kernel 2: x_proj = concat(base,visual) @ W_ih^T + b_ih, stored bf16 at
// [(k*256 + b)*3072 + n].  128x128 tile, BK=64, 256 threads.
// Epilogue staged through an LDS C-tile for fully-coalesced 16B stores.
__global__ __launch_bounds__(256, 2) void gemm_xproj(
    const float* __restrict__ base, const float* __restrict__ vis,
    const short* __restrict__ wihb, const float* __restrict__ bih,
    short* __restrict__ xp)
{
    __shared__ union {
        struct { short A[128 * 64]; short B[128 * 64]; } ab;
        short C[128 * 136];            // 136-short row stride (pad) for epilogue
    } sm;
    const int tid = threadIdx.x;
    const int bid = blockIdx.x;
    const int nt = bid % 24, mt = bid / 24;
    const int m0 = mt * 128, n0 = nt * 128;
    const int lane = tid & 63, w = tid >> 6;
    const int wm = w >> 1, wn = w & 1;
    const int l15 = lane & 15, quad = lane >> 4;

    f32x4 acc[4][4];
#pragma unroll
    for (int i = 0; i < 4; ++i)
#pragma unroll
        for (int j = 0; j < 4; ++j) acc[i][j] = (f32x4){0.f, 0.f, 0.f, 0.f};

    const int arow = tid >> 3;
    const int acol8 = (tid & 7) * 8;

    for (int kt = 0; kt < 16; ++kt) {
        const int k0 = kt * 64;
        __syncthreads();
#pragma unroll
        for (int is = 0; is < 4; ++is) {
            const int row = is * 32 + arow;
            const int col = k0 + acol8;   // block-uniform predicate (64 | 256)
            const float* s = (col < 256)
                ? (base + (size_t)(m0 + row) * 256 + col)
                : (vis  + (size_t)(m0 + row) * 768 + (col - 256));
            const float4 v0 = *(const float4*)s;
            const float4 v1 = *(const float4*)(s + 4);
            bf16x8 pk;
            pk[0] = f2bf(v0.x); pk[1] = f2bf(v0.y); pk[2] = f2bf(v0.z); pk[3] = f2bf(v0.w);
            pk[4] = f2bf(v1.x); pk[5] = f2bf(v1.y); pk[6] = f2bf(v1.z); pk[7] = f2bf(v1.w);
            *(bf16x8*)&sm.ab.A[is * 2048 + tid * 8] = pk;
            __builtin_amdgcn_global_load_lds(
                (const __attribute__((address_space(1))) void*)(wihb + (size_t)(n0 + is * 32 + (tid >> 3)) * 1024 + k0 + (tid & 7) * 8),
                (__attribute__((address_space(3))) void*)&sm.ab.B[is * 2048 + tid * 8],
                16, 0, 0);
        }
        __syncthreads();
#pragma unroll
        for (int s2 = 0; s2 < 2; ++s2) {
            bf16x8 af[4], bf[4];
#pragma unroll
            for (int i = 0; i < 4; ++i)
                af[i] = *(const bf16x8*)&sm.ab.A[(wm * 64 + i * 16 + l15) * 64 + s2 * 32 + quad * 8];
#pragma unroll
            for (int j = 0; j < 4; ++j)
                bf[j] = *(const bf16x8*)&sm.ab.B[(wn * 64 + j * 16 + l15) * 64 + s2 * 32 + quad * 8];
#pragma unroll
            for (int i = 0; i < 4; ++i)
#pragma unroll
                for (int j = 0; j < 4; ++j)
                    acc[i][j] = __builtin_amdgcn_mfma_f32_16x16x32_bf16(af[i], bf[j], acc[i][j], 0, 0, 0);
        }
    }
    __syncthreads();     // A/B dead; reuse as C-tile
#pragma unroll
    for (int j = 0; j < 4; ++j) {
        const int cn = wn * 64 + j * 16 + l15;
        const float bv = bih[n0 + cn];
#pragma unroll
        for (int i = 0; i < 4; ++i) {
            const int rb = wm * 64 + i * 16 + quad * 4;
#pragma unroll
            for (int r = 0; r < 4; ++r)
                sm.C[(rb + r) * 136 + cn] = f2bf(acc[i][j][r] + bv);
        }
    }
    __syncthreads();
    // cooperative coalesced store: thread -> (row, 64-col half), 8 x 16B
    {
        const int row = tid >> 1, c0 = (tid & 1) * 64;
        const int gm = m0 + row;
        short* dst = xp + ((size_t)(gm & 127) * 256 + (size_t)(gm >> 7)) * 3072 + n0 + c0;
        const short* src = &sm.C[row * 136 + c0];
#pragma unroll
        for (int c = 0; c < 64; c += 8)
            *(bf16x8*)(dst + c) = *(const bf16x8*)(src + c);
    }
}

// ---------------------------------------------------------------------------
// Kernel 3: persistent GRU recurrence. 256 blocks (1/CU) x 256 threads.
// Block = (bt 0..7, ct 0..31): 32 batch rows x 32 h-cols (96 gate cols).
// W_hh slice in registers for all 128 steps. h exchange through coherent LLC
// (sc0sc1 stores/loads).
// Sync layout (INTERLEAVED, fits the original 4 KB region — workspace map is
// byte-identical to the last passing kernel): flag dword = ct*32 + bt*4,
// i.e. byte addr = ct*128 + bt*16.  Within one batch group (the 32 producers
// that gate a consumer) all flags live on 32 DISTINCT 128B lines, so the
// gating stores land in parallel at the LLC (the old packed layout serialized
// all 32 coherent stores on one line; the consumer is gated by the LAST one).
// Cross-group sharing is <=8 producers/line and those are not barrier-coupled.
// Only wave 0 polls (s_sleep backoff); waves 1-3 park at a barrier — cuts
// coherent poll traffic 4x+ and keeps the LLC queue short.
// ALL async asm loads have their destinations tied to a s_waitcnt asm before
// first use (register-lifetime hazard — R4's NaN came from untied xn_).
__global__ __launch_bounds__(256, 1) void gru_rec(
    const short* __restrict__ xp, const short* __restrict__ whhb,
    const float* __restrict__ bhh, short* __restrict__ hbuf,   // 2 x 256*1024 bf16, zeroed
    float* __restrict__ out, unsigned* __restrict__ flags)     // 4 KB interleaved flags, zeroed
{
    __shared__ float red[128 * RS];   // 51200 B split-K partials, padded stride
    const int tid = threadIdx.x;
    const int bid = blockIdx.x;
    const int bt = bid >> 5;       // batch group 0..7
    const int ct = bid & 31;       // col block  0..31
    const int lane = tid & 63, w = tid >> 6;
    const int l15 = lane & 15, quad = lane >> 4;
    const int bm0 = bt * 32;
    const int kbase = w * 256 + quad * 8;   // this wave's K-chunk

    // persistent W_hh fragments: 6 n-tiles x 8 k-iters (192 VGPRs)
    bf16x8 Bf[6][8];
#pragma unroll
    for (int g = 0; g < 6; ++g) {
        const size_t col = (size_t)((g >> 1) * 1024 + ct * 32 + (g & 1) * 16 + l15);
#pragma unroll
        for (int kk = 0; kk < 8; ++kk)
            Bf[g][kk] = *(const bf16x8*)(whhb + col * 1024 + kbase + kk * 32);
    }

    // epilogue ownership: 1 row x 4 consecutive cols per thread
    const int er = tid >> 3;             // row within group, 0..31
    const int ec0 = (tid & 7) * 4;       // first col, 0..28
    const f32x4 bhr = *(const f32x4*)(bhh + ct * 32 + ec0);
    const f32x4 bhz = *(const f32x4*)(bhh + 1024 + ct * 32 + ec0);
    const f32x4 bhn = *(const f32x4*)(bhh + 2048 + ct * 32 + ec0);

    // interleaved flag layout: dword index = ct*32 + bt*4 (4 KB total)
    unsigned* const myflag = flags + (size_t)ct * 32 + bt * 4;
    const unsigned* const pollp = flags + (size_t)(lane & 31) * 32 + bt * 4;

    float hold[4] = {0.f, 0.f, 0.f, 0.f};
    s16x4 xc[3], xn_[3];
    {
        const size_t rb = (size_t)(bm0 + er) * 3072 + ct * 32 + ec0;
#pragma unroll
        for (int g = 0; g < 3; ++g) xc[g] = *(const s16x4*)(xp + rb + g * 1024);
    }

    for (int step = 0; step < 128; ++step) {
        // --- wait for step's h (producers flagged `step`); step 0 pre-zeroed ---
        // Wave 0 polls for the whole block; backoff keeps the LLC queue short.
        if (step > 0) {
            if (w == 0) {
                const unsigned tgt = (unsigned)step;
                unsigned fv;
                for (;;) {
                    asm volatile("global_load_dword %0, %1, off sc0 sc1" : "=v"(fv) : "v"(pollp));
                    asm volatile("s_waitcnt vmcnt(0)" : "+v"(fv) :: "memory");
                    if (!__ballot(fv < tgt)) break;
                    __builtin_amdgcn_s_sleep(1);
                }
            }
            __syncthreads();   // release waves 1-3 once wave 0 saw all 32 flags
        }
        const short* hr_ = hbuf + (size_t)(step & 1) * (256 * 1024);
        short* hw_ = hbuf + (size_t)((step + 1) & 1) * (256 * 1024);

        // --- h loads: 16 LLC-bypass b128 loads, one tied waitcnt ---
        bf16x8 A0[8], A1[8];
        const short* p0 = hr_ + (size_t)(bm0 + l15) * 1024 + kbase;
        const short* p1 = p0 + 16 * 1024;
        LDH(A0[0], p0, "0");   LDH(A0[1], p0, "64");  LDH(A0[2], p0, "128"); LDH(A0[3], p0, "192");
        LDH(A0[4], p0, "256"); LDH(A0[5], p0, "320"); LDH(A0[6], p0, "384"); LDH(A0[7], p0, "448");
        LDH(A1[0], p1, "0");   LDH(A1[1], p1, "64");  LDH(A1[2], p1, "128"); LDH(A1[3], p1, "192");
        LDH(A1[4], p1, "256"); LDH(A1[5], p1, "320"); LDH(A1[6], p1, "384"); LDH(A1[7], p1, "448");
        asm volatile("s_waitcnt vmcnt(0)"
            : "+v"(A0[0]), "+v"(A0[1]), "+v"(A0[2]), "+v"(A0[3]),
              "+v"(A0[4]), "+v"(A0[5]), "+v"(A0[6]), "+v"(A0[7]),
              "+v"(A1[0]), "+v"(A1[1]), "+v"(A1[2]), "+v"(A1[3]),
              "+v"(A1[4]), "+v"(A1[5]), "+v"(A1[6]), "+v"(A1[7])
            :: "memory");
        // early xp prefetch for step+1: a full step of compute to hide HBM miss.
        // Destinations are tied to the store-drain waitcnt below before use.
        if (step < 127) {
            const short* rb = xp + ((size_t)(step + 1) * 256 + bm0 + er) * 3072 + ct * 32 + ec0;
            LDX(xn_[0], rb); LDX(xn_[1], rb + 1024); LDX(xn_[2], rb + 2048);
        }

        f32x4 acc[2][6];
#pragma unroll
        for (int i = 0; i < 2; ++i)
#pragma unroll
            for (int g = 0; g < 6; ++g) acc[i][g] = (f32x4){0.f, 0.f, 0.f, 0.f};
#pragma unroll
        for (int kk = 0; kk < 8; ++kk) {
#pragma unroll
            for (int g = 0; g < 6; ++g) {
                acc[0][g] = __builtin_amdgcn_mfma_f32_16x16x32_bf16(A0[kk], Bf[g][kk], acc[0][g], 0, 0, 0);
                acc[1][g] = __builtin_amdgcn_mfma_f32_16x16x32_bf16(A1[kk], Bf[g][kk], acc[1][g], 0, 0, 0);
            }
        }
        // split-K partials -> LDS (padded stride: 2-way max, conflict-free)
#pragma unroll
        for (int i = 0; i < 2; ++i)
#pragma unroll
            for (int g = 0; g < 6; ++g) {
                const int c96 = (g >> 1) * 32 + (g & 1) * 16 + l15;
                const int rb = w * 32 + i * 16 + quad * 4;
#pragma unroll
                for (int r = 0; r < 4; ++r)
                    red[(rb + r) * RS + c96] = acc[i][g][r];
            }
        __syncthreads();
        // reduce 4 split-K partials + gates + state update
        f32x4 sr = bhr, sz = bhz, sn = bhn;
#pragma unroll
        for (int ww = 0; ww < 4; ++ww) {
            const float* rbp = &red[(ww * 32 + er) * RS];
            sr += *(const f32x4*)(rbp + ec0);
            sz += *(const f32x4*)(rbp + 32 + ec0);
            sn += *(const f32x4*)(rbp + 64 + ec0);
        }
        s16x4 hpk;
#pragma unroll
        for (int i = 0; i < 4; ++i) {
            const float xr = bf2f((unsigned short)xc[0][i]);
            const float xz = bf2f((unsigned short)xc[1][i]);
            const float xnv = bf2f((unsigned short)xc[2][i]);
            const float rg = 1.f / (1.f + __expf(-(xr + sr[i])));
            const float zg = 1.f / (1.f + __expf(-(xz + sz[i])));
            const float e2 = __expf(2.f * (xnv + rg * sn[i]));
            const float ng = 1.f - 2.f / (e2 + 1.f);   // tanh, overflow-safe
            const float hv = (1.f - zg) * ng + zg * hold[i];
            hold[i] = hv;
            hpk[i] = f2bf(hv);
        }
        if (step < 127) {
            st_llc_b64(&hw_[(size_t)(bm0 + er) * 1024 + ct * 32 + ec0], hpk);
            // drain h store AND the xn_ prefetch; tying xn_ here (a) pins the
            // registers until the data has landed, (b) makes the xc copy below
            // data-dependent on the drain (cannot be hoisted).
            asm volatile("s_waitcnt vmcnt(0)"
                : "+v"(xn_[0]), "+v"(xn_[1]), "+v"(xn_[2]) :: "memory");
            __syncthreads();                                   // all waves drained
            if (tid == 0) st_llc_b32(myflag, (unsigned)(step + 1));
            xc[0] = xn_[0]; xc[1] = xn_[1]; xc[2] = xn_[2];
        } else {
            __syncthreads();   // uniformity on last step (cheap)
        }
    }
    float4 o4; o4.x = hold[0]; o4.y = hold[1]; o4.z = hold[2]; o4.w = hold[3];
    *(float4*)(out + (size_t)(bm0 + er) * 1024 + ct * 32 + ec0) = o4;
}

// ---------------------------------------------------------------------------
extern "C" void kernel_launch(void* const* d_in, const int* in_sizes, int n_in,
                              void* d_out, int out_size, void* d_ws, size_t ws_size,
                              hipStream_t stream) {
    (void)in_sizes; (void)n_in; (void)out_size; (void)ws_size;
    const float* base = (const float*)d_in[0];
    const float* vis  = (const float*)d_in[1];
    const float* wih  = (const float*)d_in[2];
    const float* whh  = (const float*)d_in[3];
    const float* bih  = (const float*)d_in[4];
    const float* bhh  = (const float*)d_in[5];

    char* ws = (char*)d_ws;
    short*    xp   = (short*)(ws + 0);                    // 201326592 B
    short*    wihb = (short*)(ws + 201326592);            //   6291456 B
    short*    whhb = (short*)(ws + 207618048);            //   6291456 B
    short*    hbuf = (short*)(ws + 213909504);            //   1048576 B (ping-pong)
    unsigned* flg  = (unsigned*)(ws + 214958080);         //      4096 B (interleaved flags)

    hipMemsetAsync(hbuf, 0, 1048576, stream);             // h0 = 0 (both buffers)
    hipMemsetAsync(flg, 0, 4096, stream);                 // flags

    cvt_w<<<dim3(6144), dim3(256), 0, stream>>>(wih, whh, wihb, whhb);
    gemm_xproj<<<dim3(6144), dim3(256), 0, stream>>>(base, vis, wihb, bih, xp);
    gru_rec<<<dim3(256), dim3(256), 0, stream>>>(xp, whhb, bhh, hbuf, (float*)d_out, flg);
}

// Round 4
// 1191.535 us; speedup vs baseline: 1.1013x; 1.1013x over previous
//
#include <hip/hip_runtime.h>

// Problem constants
#define BATCH 256
#define SEQ   128
#define IDIM  1024     // 256 + 768
#define HDIM  1024
#define G3    3072     // 3*HDIM
#define RS    100      // padded row stride (dwords) of split-K LDS buffer

typedef __attribute__((ext_vector_type(8))) short bf16x8;
typedef __attribute__((ext_vector_type(4))) short s16x4;
typedef __attribute__((ext_vector_type(4))) float f32x4;

__device__ __forceinline__ short f2bf(float f) {
    union { float f; unsigned u; } x; x.f = f;
    unsigned r = x.u + 0x7fffu + ((x.u >> 16) & 1u);   // RNE
    return (short)(r >> 16);
}
__device__ __forceinline__ float bf2f(unsigned short u) {
    union { unsigned u; float f; } x; x.u = ((unsigned)u) << 16;
    return x.f;
}

// LLC-coherent ops: write-through / bypass L1+L2, coherent at Infinity Cache.
__device__ __forceinline__ void st_llc_b64(short* p, s16x4 v) {
    asm volatile("global_store_dwordx2 %0, %1, off sc0 sc1" :: "v"(p), "v"(v) : "memory");
}
__device__ __forceinline__ void st_llc_b32(unsigned* p, unsigned v) {
    asm volatile("global_store_dword %0, %1, off sc0 sc1" :: "v"(p), "v"(v) : "memory");
}
#define LDH(dst, p, OFF) \
    asm volatile("global_load_dwordx4 %0, %1, off offset:" OFF " sc0 sc1" \
                 : "=v"(dst) : "v"(p))
#define LDX(dst, p) \
    asm volatile("global_load_dwordx2 %0, %1, off" : "=v"(dst) : "v"(p))

// ---------------------------------------------------------------------------
// Kernel 1: convert W_ih and W_hh (f32, row-major (3072,1024)) to bf16.
__global__ void cvt_w(const float* __restrict__ wih, const float* __restrict__ whh,
                      short* __restrict__ wihb, short* __restrict__ whhb) {
    int i = blockIdx.x * 256 + threadIdx.x;
    const float* s; short* d; int j;
    if (i < 786432) { s = wih; d = wihb; j = i; }
    else            { s = whh; d = whhb; j = i - 786432; }
    const float4 v = *((const float4*)s + j);
    s16x4 o;
    o[0] = f2bf(v.x); o[1] = f2bf(v.y); o[2] = f2bf(v.z); o[3] = f2bf(v.w);
    *(s16x4*)(d + (size_t)j * 4) = o;
}

// ---------------------------------------------------------------------------
// Kernel 2: x_proj = concat(base,visual) @ W_ih^T + b_ih, stored bf16 at
// [(k*256 + b)*3072 + n].  128x128 tile, BK=64, 256 threads.
// v2: minimum 2-phase pipeline (guide T3-lite) — double-buffered A/B LDS
// tiles, stage(t+1) issued BEFORE compute(t), A f32 data prefetched into
// registers one full iteration ahead, and f32->bf16 packing via
// v_cvt_pk_bf16_f32 (4 instrs / 16B instead of ~24 manual bit-ops; same RNE).
// Epilogue staged through an LDS C-tile for fully-coalesced 16B stores.
__global__ __launch_bounds__(256, 2) void gemm_xproj(
    const float* __restrict__ base, const float* __restrict__ vis,
    const short* __restrict__ wihb, const float* __restrict__ bih,
    short* __restrict__ xp)
{
    __shared__ union {
        struct { short A[2][128 * 64]; short B[2][128 * 64]; } ab;   // 64 KB dbuf
        short C[128 * 136];            // 136-short row stride (pad) for epilogue
    } sm;
    const int tid = threadIdx.x;
    const int bid = blockIdx.x;
    const int nt = bid % 24, mt = bid / 24;
    const int m0 = mt * 128, n0 = nt * 128;
    const int lane = tid & 63, w = tid >> 6;
    const int wm = w >> 1, wn = w & 1;
    const int l15 = lane & 15, quad = lane >> 4;

    f32x4 acc[4][4];
#pragma unroll
    for (int i = 0; i < 4; ++i)
#pragma unroll
        for (int j = 0; j < 4; ++j) acc[i][j] = (f32x4){0.f, 0.f, 0.f, 0.f};

    const int arow = tid >> 3;          // 0..31
    const int acol8 = (tid & 7) * 8;    // 0..56

    float4 pv0[4], pv1[4];              // A f32 prefetch regs (next K-tile)

    // issue the 8 global f32x4 A-loads for K-tile kt into pv
    auto issueA = [&](int kt) {
        const int col = kt * 64 + acol8;    // block-uniform predicate (64 | 256)
#pragma unroll
        for (int is = 0; is < 4; ++is) {
            const int row = m0 + is * 32 + arow;
            const float* s = (col < 256)
                ? (base + (size_t)row * 256 + col)
                : (vis  + (size_t)row * 768 + (col - 256));
            pv0[is] = *(const float4*)s;
            pv1[is] = *(const float4*)(s + 4);
        }
    };
    // consume pv -> bf16 A tile in LDS buf; B tile via global_load_lds
    auto stage = [&](int buf, int kt) {
        const int k0 = kt * 64;
#pragma unroll
        for (int is = 0; is < 4; ++is) {
            union { unsigned u[4]; bf16x8 v; } pk;
            asm("v_cvt_pk_bf16_f32 %0, %1, %2" : "=v"(pk.u[0]) : "v"(pv0[is].x), "v"(pv0[is].y));
            asm("v_cvt_pk_bf16_f32 %0, %1, %2" : "=v"(pk.u[1]) : "v"(pv0[is].z), "v"(pv0[is].w));
            asm("v_cvt_pk_bf16_f32 %0, %1, %2" : "=v"(pk.u[2]) : "v"(pv1[is].x), "v"(pv1[is].y));
            asm("v_cvt_pk_bf16_f32 %0, %1, %2" : "=v"(pk.u[3]) : "v"(pv1[is].z), "v"(pv1[is].w));
            *(bf16x8*)&sm.ab.A[buf][is * 2048 + tid * 8] = pk.v;
            __builtin_amdgcn_global_load_lds(
                (const __attribute__((address_space(1))) void*)(wihb + (size_t)(n0 + is * 32 + arow) * 1024 + k0 + acol8),
                (__attribute__((address_space(3))) void*)&sm.ab.B[buf][is * 2048 + tid * 8],
                16, 0, 0);
        }
    };

    // prologue: tile 0 staged, tile 1's A f32 in flight
    issueA(0);
    stage(0, 0);
    issueA(1);
    __syncthreads();

    for (int kt = 0; kt < 16; ++kt) {
        const int cur = kt & 1, nxt = cur ^ 1;
        // stage next tile FIRST (into the other buffer — its readers passed
        // the previous barrier), so its latency hides under this compute.
        if (kt < 15) {
            stage(nxt, kt + 1);          // consumes pv (kt+1 data)
            if (kt < 14) issueA(kt + 2); // refill pv for the next stage
        }
#pragma unroll
        for (int s2 = 0; s2 < 2; ++s2) {
            bf16x8 af[4], bfv[4];
#pragma unroll
            for (int i = 0; i < 4; ++i)
                af[i] = *(const bf16x8*)&sm.ab.A[cur][(wm * 64 + i * 16 + l15) * 64 + s2 * 32 + quad * 8];
#pragma unroll
            for (int j = 0; j < 4; ++j)
                bfv[j] = *(const bf16x8*)&sm.ab.B[cur][(wn * 64 + j * 16 + l15) * 64 + s2 * 32 + quad * 8];
#pragma unroll
            for (int i = 0; i < 4; ++i)
#pragma unroll
                for (int j = 0; j < 4; ++j)
                    acc[i][j] = __builtin_amdgcn_mfma_f32_16x16x32_bf16(af[i], bfv[j], acc[i][j], 0, 0, 0);
        }
        __syncthreads();   // stage(nxt) writes drained; buf roles swap
    }
    // A/B dead; reuse union as C-tile (last barrier above already passed)
#pragma unroll
    for (int j = 0; j < 4; ++j) {
        const int cn = wn * 64 + j * 16 + l15;
        const float bv = bih[n0 + cn];
#pragma unroll
        for (int i = 0; i < 4; ++i) {
            const int rb = wm * 64 + i * 16 + quad * 4;
#pragma unroll
            for (int r = 0; r < 4; ++r)
                sm.C[(rb + r) * 136 + cn] = f2bf(acc[i][j][r] + bv);
        }
    }
    __syncthreads();
    // cooperative coalesced store: thread -> (row, 64-col half), 8 x 16B
    {
        const int row = tid >> 1, c0 = (tid & 1) * 64;
        const int gm = m0 + row;
        short* dst = xp + ((size_t)(gm & 127) * 256 + (size_t)(gm >> 7)) * 3072 + n0 + c0;
        const short* src = &sm.C[row * 136 + c0];
#pragma unroll
        for (int c = 0; c < 64; c += 8)
            *(bf16x8*)(dst + c) = *(const bf16x8*)(src + c);
    }
}

// ---------------------------------------------------------------------------
// Kernel 3: persistent GRU recurrence. 256 blocks (1/CU) x 256 threads.
// Block = (bt 0..7, ct 0..31): 32 batch rows x 32 h-cols (96 gate cols).
// W_hh slice in registers for all 128 steps. h exchange through coherent LLC
// (sc0sc1 stores/loads). Sync = per-block flags packed in one 128B line per
// batch group, monotone step values, polled by all waves with one coalesced
// bypass load + ballot. ZERO cache flush/inv ops, ZERO same-address RMW.
// [EXACT revert to the proven 716us R0 configuration — R1/R3 variants both
//  killed the container; suspected sc0-scope hang / unscreened verify spin.]
// ALL async asm loads have their destinations tied to a s_waitcnt asm before
// first use (register-lifetime hazard — R4's NaN came from untied xn_).
__global__ __launch_bounds__(256, 1) void gru_rec(
    const short* __restrict__ xp, const short* __restrict__ whhb,
    const float* __restrict__ bhh, short* __restrict__ hbuf,   // 2 x 256*1024 bf16, zeroed
    float* __restrict__ out, unsigned* __restrict__ flags)     // 8*32 flags, zeroed
{
    __shared__ float red[128 * RS];   // 51200 B split-K partials, padded stride
    const int tid = threadIdx.x;
    const int bid = blockIdx.x;
    const int bt = bid >> 5;       // batch group 0..7
    const int ct = bid & 31;       // col block  0..31
    const int lane = tid & 63, w = tid >> 6;
    const int l15 = lane & 15, quad = lane >> 4;
    const int bm0 = bt * 32;
    const int kbase = w * 256 + quad * 8;   // this wave's K-chunk

    // persistent W_hh fragments: 6 n-tiles x 8 k-iters (192 VGPRs)
    bf16x8 Bf[6][8];
#pragma unroll
    for (int g = 0; g < 6; ++g) {
        const size_t col = (size_t)((g >> 1) * 1024 + ct * 32 + (g & 1) * 16 + l15);
#pragma unroll
        for (int kk = 0; kk < 8; ++kk)
            Bf[g][kk] = *(const bf16x8*)(whhb + col * 1024 + kbase + kk * 32);
    }

    // epilogue ownership: 1 row x 4 consecutive cols per thread
    const int er = tid >> 3;             // row within group, 0..31
    const int ec0 = (tid & 7) * 4;       // first col, 0..28
    const f32x4 bhr = *(const f32x4*)(bhh + ct * 32 + ec0);
    const f32x4 bhz = *(const f32x4*)(bhh + 1024 + ct * 32 + ec0);
    const f32x4 bhn = *(const f32x4*)(bhh + 2048 + ct * 32 + ec0);

    unsigned* const myflag = flags + bt * 32 + ct;
    const unsigned* const pollp = flags + bt * 32 + (lane & 31);

    float hold[4] = {0.f, 0.f, 0.f, 0.f};
    s16x4 xc[3], xn_[3];
    {
        const size_t rb = (size_t)(bm0 + er) * 3072 + ct * 32 + ec0;
#pragma unroll
        for (int g = 0; g < 3; ++g) xc[g] = *(const s16x4*)(xp + rb + g * 1024);
    }

    for (int step = 0; step < 128; ++step) {
        // --- wait for step's h (producers flagged `step`); step 0 pre-zeroed ---
        if (step > 0) {
            const unsigned tgt = (unsigned)step;
            unsigned fv;
            do {
                asm volatile("global_load_dword %0, %1, off sc0 sc1" : "=v"(fv) : "v"(pollp));
                asm volatile("s_waitcnt vmcnt(0)" : "+v"(fv) :: "memory");
            } while (__ballot(fv < tgt));
        }
        const short* hr_ = hbuf + (size_t)(step & 1) * (256 * 1024);
        short* hw_ = hbuf + (size_t)((step + 1) & 1) * (256 * 1024);

        // --- h loads: 16 LLC-bypass b128 loads, one tied waitcnt ---
        bf16x8 A0[8], A1[8];
        const short* p0 = hr_ + (size_t)(bm0 + l15) * 1024 + kbase;
        const short* p1 = p0 + 16 * 1024;
        LDH(A0[0], p0, "0");   LDH(A0[1], p0, "64");  LDH(A0[2], p0, "128"); LDH(A0[3], p0, "192");
        LDH(A0[4], p0, "256"); LDH(A0[5], p0, "320"); LDH(A0[6], p0, "384"); LDH(A0[7], p0, "448");
        LDH(A1[0], p1, "0");   LDH(A1[1], p1, "64");  LDH(A1[2], p1, "128"); LDH(A1[3], p1, "192");
        LDH(A1[4], p1, "256"); LDH(A1[5], p1, "320"); LDH(A1[6], p1, "384"); LDH(A1[7], p1, "448");
        asm volatile("s_waitcnt vmcnt(0)"
            : "+v"(A0[0]), "+v"(A0[1]), "+v"(A0[2]), "+v"(A0[3]),
              "+v"(A0[4]), "+v"(A0[5]), "+v"(A0[6]), "+v"(A0[7]),
              "+v"(A1[0]), "+v"(A1[1]), "+v"(A1[2]), "+v"(A1[3]),
              "+v"(A1[4]), "+v"(A1[5]), "+v"(A1[6]), "+v"(A1[7])
            :: "memory");
        // early xp prefetch for step+1: a full step of compute to hide HBM miss.
        // Destinations are tied to the store-drain waitcnt below before use.
        if (step < 127) {
            const short* rb = xp + ((size_t)(step + 1) * 256 + bm0 + er) * 3072 + ct * 32 + ec0;
            LDX(xn_[0], rb); LDX(xn_[1], rb + 1024); LDX(xn_[2], rb + 2048);
        }

        f32x4 acc[2][6];
#pragma unroll
        for (int i = 0; i < 2; ++i)
#pragma unroll
            for (int g = 0; g < 6; ++g) acc[i][g] = (f32x4){0.f, 0.f, 0.f, 0.f};
#pragma unroll
        for (int kk = 0; kk < 8; ++kk) {
#pragma unroll
            for (int g = 0; g < 6; ++g) {
                acc[0][g] = __builtin_amdgcn_mfma_f32_16x16x32_bf16(A0[kk], Bf[g][kk], acc[0][g], 0, 0, 0);
                acc[1][g] = __builtin_amdgcn_mfma_f32_16x16x32_bf16(A1[kk], Bf[g][kk], acc[1][g], 0, 0, 0);
            }
        }
        // split-K partials -> LDS (padded stride: 2-way max, conflict-free)
#pragma unroll
        for (int i = 0; i < 2; ++i)
#pragma unroll
            for (int g = 0; g < 6; ++g) {
                const int c96 = (g >> 1) * 32 + (g & 1) * 16 + l15;
                const int rb = w * 32 + i * 16 + quad * 4;
#pragma unroll
                for (int r = 0; r < 4; ++r)
                    red[(rb + r) * RS + c96] = acc[i][g][r];
            }
        __syncthreads();
        // reduce 4 split-K partials + gates + state update
        f32x4 sr = bhr, sz = bhz, sn = bhn;
#pragma unroll
        for (int ww = 0; ww < 4; ++ww) {
            const float* rbp = &red[(ww * 32 + er) * RS];
            sr += *(const f32x4*)(rbp + ec0);
            sz += *(const f32x4*)(rbp + 32 + ec0);
            sn += *(const f32x4*)(rbp + 64 + ec0);
        }
        s16x4 hpk;
#pragma unroll
        for (int i = 0; i < 4; ++i) {
            const float xr = bf2f((unsigned short)xc[0][i]);
            const float xz = bf2f((unsigned short)xc[1][i]);
            const float xnv = bf2f((unsigned short)xc[2][i]);
            const float rg = 1.f / (1.f + __expf(-(xr + sr[i])));
            const float zg = 1.f / (1.f + __expf(-(xz + sz[i])));
            const float e2 = __expf(2.f * (xnv + rg * sn[i]));
            const float ng = 1.f - 2.f / (e2 + 1.f);   // tanh, overflow-safe
            const float hv = (1.f - zg) * ng + zg * hold[i];
            hold[i] = hv;
            hpk[i] = f2bf(hv);
        }
        if (step < 127) {
            st_llc_b64(&hw_[(size_t)(bm0 + er) * 1024 + ct * 32 + ec0], hpk);
            // drain h store AND the xn_ prefetch; tying xn_ here (a) pins the
            // registers until the data has landed, (b) makes the xc copy below
            // data-dependent on the drain (cannot be hoisted).
            asm volatile("s_waitcnt vmcnt(0)"
                : "+v"(xn_[0]), "+v"(xn_[1]), "+v"(xn_[2]) :: "memory");
            __syncthreads();                                   // all waves drained
            if (tid == 0) st_llc_b32(myflag, (unsigned)(step + 1));
            xc[0] = xn_[0]; xc[1] = xn_[1]; xc[2] = xn_[2];
        } else {
            __syncthreads();   // uniformity on last step (cheap)
        }
    }
    float4 o4; o4.x = hold[0]; o4.y = hold[1]; o4.z = hold[2]; o4.w = hold[3];
    *(float4*)(out + (size_t)(bm0 + er) * 1024 + ct * 32 + ec0) = o4;
}

// ---------------------------------------------------------------------------
extern "C" void kernel_launch(void* const* d_in, const int* in_sizes, int n_in,
                              void* d_out, int out_size, void* d_ws, size_t ws_size,
                              hipStream_t stream) {
    (void)in_sizes; (void)n_in; (void)out_size; (void)ws_size;
    const float* base = (const float*)d_in[0];
    const float* vis  = (const float*)d_in[1];
    const float* wih  = (const float*)d_in[2];
    const float* whh  = (const float*)d_in[3];
    const float* bih  = (const float*)d_in[4];
    const float* bhh  = (const float*)d_in[5];

    char* ws = (char*)d_ws;
    short*    xp   = (short*)(ws + 0);                    // 201326592 B
    short*    wihb = (short*)(ws + 201326592);            //   6291456 B
    short*    whhb = (short*)(ws + 207618048);            //   6291456 B
    short*    hbuf = (short*)(ws + 213909504);            //   1048576 B (ping-pong)
    unsigned* flg  = (unsigned*)(ws + 214958080);         //      4096 B

    hipMemsetAsync(hbuf, 0, 1048576, stream);             // h0 = 0 (both buffers)
    hipMemsetAsync(flg, 0, 4096, stream);                 // flags

    cvt_w<<<dim3(6144), dim3(256), 0, stream>>>(wih, whh, wihb, whhb);
    gemm_xproj<<<dim3(6144), dim3(256), 0, stream>>>(base, vis, wihb, bih, xp);
    gru_rec<<<dim3(256), dim3(256), 0, stream>>>(xp, whhb, bhh, hbuf, (float*)d_out, flg);
}